// Round 19
// baseline (176.575 us; speedup 1.0000x reference)
//
#include <hip/hip_runtime.h>
#include <hip/hip_bf16.h>

constexpr int D_ = 128;
constexpr int DK_ = 16;
constexpr int TBL = 4096;

typedef __attribute__((ext_vector_type(8))) short short8;
typedef __attribute__((ext_vector_type(4))) float f32x4;
typedef unsigned char uchar;

__device__ __forceinline__ ushort f2b(float f) {
    uint b = __float_as_uint(f);
    uint r = (b + 0x7fffu + ((b >> 16) & 1u)) >> 16;
    return (ushort)r;
}
// fixed-scale biased int8: byte = clamp(round(v*31.75)+128, 0, 255)
__device__ __forceinline__ uchar q8(float v) {
    float t = fmaf(v, 31.75f, 128.5f);
    t = fminf(fmaxf(t, 0.0f), 255.0f);
    return (uchar)(uint)t;
}
__device__ __forceinline__ float fexp2(float x) {
#if __has_builtin(__builtin_amdgcn_exp2f)
    return __builtin_amdgcn_exp2f(x);
#else
    return exp2f(x);
#endif
}
__device__ __forceinline__ float frcp(float x) {
#if __has_builtin(__builtin_amdgcn_rcpf)
    return __builtin_amdgcn_rcpf(x);
#else
    return 1.0f / x;
#endif
}

// ================= D1: homogeneous fused front (R14/R16 config: 1 edge/thread) =================
__global__ __launch_bounds__(256)
void k_front(const float2* __restrict__ x2, uint* __restrict__ xnb,
             const float* __restrict__ Wk, const float* __restrict__ Wv,
             uchar* __restrict__ gkv,
             const float* __restrict__ Wq, const float* __restrict__ bq,
             const float* __restrict__ bk, const float* __restrict__ bv,
             ushort* __restrict__ WTb, float* __restrict__ BB,
             const int* __restrict__ ei, const float* __restrict__ ewt,
             const float* __restrict__ etime,
             int* __restrict__ cnt, float* __restrict__ deg, uint2* __restrict__ pp2,
             int N, int E, int RPB) {
    __shared__ float te[16][128];
    __shared__ int sor;
    int b = blockIdx.x;
    int tid = threadIdx.x;
    int wv = tid >> 6, lane = tid & 63;

    // ---- phase A: edge atomics ----
    int2 det = ((const int2*)ei)[tid];   // fixed window, words < 512 <= 2E: safe both layouts
    if (tid == 0) sor = 0;
    __syncthreads();
    atomicOr(&sor, det.y);               // all odd words zero => int64 layout
    __syncthreads();
    int e = b * 256 + tid;
    bool act = (e < E);
    int s = 0, dd = 0, rank = 0;
    float t = 0.f;
    if (act) {
        if (sor == 0) { s = ((const int2*)ei)[e].x; dd = ((const int2*)ei)[E + e].x; }
        else          { s = ei[e];                  dd = ei[E + e]; }
        t = etime[e];
        atomicAdd(&deg[s], ewt[e]);          // fire-and-forget
        rank = atomicAdd(&cnt[dd], 1);       // return hidden under phase B
    }

    // ---- phase B: VALU work ----
    if (b < TBL / 16) {
        // temporal table -> gkv[TBL][256] int8 interleaved [k4|v4], 16 rows/block
        int t0 = b * 16;
        int j = tid & 127, half = tid >> 7;
        float freq = 200.0f * exp2f(-(float)(j >> 1) * (13.287712379549449f / 64.0f));
        bool isCos = (j & 1);
        #pragma unroll
        for (int bb = 0; bb < 8; ++bb) {
            float tt = (float)(t0 + half * 8 + bb) * (1.0f / (float)(TBL - 1));
            float arg = tt * freq;
            te[half * 8 + bb][j] = isCos ? cosf(arg) : sinf(arg);
        }
        __syncthreads();
        int h = j >> 4, kk = j & 15;
        float ak[8] = {}, av[8] = {};
        for (int d = 0; d < 128; ++d) {
            float wk = Wk[(h * 128 + d) * 16 + kk];
            float wvv = Wv[(h * 128 + d) * 16 + kk];
            float tvs[8];
            #pragma unroll
            for (int bb = 0; bb < 8; ++bb) tvs[bb] = te[half * 8 + bb][d];
            #pragma unroll
            for (int bb = 0; bb < 8; ++bb) { ak[bb] += tvs[bb] * wk; av[bb] += tvs[bb] * wvv; }
        }
        int off = ((j >> 2) << 3) + (j & 3);
        #pragma unroll
        for (int bb = 0; bb < 8; ++bb) {
            size_t row = (size_t)(t0 + half * 8 + bb);
            gkv[row * 256 + off]     = q8(ak[bb]);
            gkv[row * 256 + off + 4] = q8(av[bb]);
        }
    } else if (b < TBL / 16 + 192) {
        // WTb[384][128] bf16 (B^T), BB[384]; 192 blocks x 256 = 384*128
        int i = (b - TBL / 16) * 256 + tid;
        int c = i >> 7, d = i & 127;
        int m = c >> 7, cl = c & 127;
        int h = cl >> 4, kk = cl & 15;
        const float* W = (m == 0) ? Wq : ((m == 1) ? Wk : Wv);
        WTb[i] = f2b(W[(h * D_ + d) * DK_ + kk]);
        if (i < 384) {
            int m2 = i >> 7, cl2 = i & 127;
            const float* bb = (m2 == 0) ? bq : ((m2 == 1) ? bk : bv);
            BB[i] = bb[cl2];
        }
    } else {
        // LayerNorm: RPB rows per block, one row per wave per iteration
        int lnb = b - (TBL / 16 + 192);
        for (int i = 0;; ++i) {
            int rl = i * 4 + wv;
            if (rl >= RPB) break;
            int row = lnb * RPB + rl;
            if (row >= N) break;
            float2 v = x2[(size_t)row * 64 + lane];
            float sm = v.x + v.y;
            #pragma unroll
            for (int o = 1; o < 64; o <<= 1) sm += __shfl_xor(sm, o);
            float mu = sm * (1.0f / 128.0f);
            float dx = v.x - mu, dy = v.y - mu;
            float s2 = dx * dx + dy * dy;
            #pragma unroll
            for (int o = 1; o < 64; o <<= 1) s2 += __shfl_xor(s2, o);
            float rs = rsqrtf(s2 * (1.0f / 128.0f) + 1e-5f);
            uint lo = f2b(dx * rs), hi = f2b(dy * rs);
            xnb[(size_t)row * 64 + lane] = (hi << 16) | lo;
        }
    }

    // ---- phase C: packed edge record (rank's wait lands here, already drained) ----
    if (act) {
        int ti = (int)(t * (float)(TBL - 1) + 0.5f);
        ti = ti < 0 ? 0 : (ti > TBL - 1 ? TBL - 1 : ti);
        uint2 r;
        r.x = (uint)s | ((uint)dd << 16);    // N <= 65536
        r.y = (uint)rank | ((uint)ti << 16); // rank < 65536, ti < 4096
        pp2[e] = r;
    }
}

// ================= D2: MFMA GEMM — A staged once, q/k/v looped, B direct from L2 ========
__global__ __launch_bounds__(256)
void k_gemm(const ushort* __restrict__ xnb, const ushort* __restrict__ WTb,
            const float* __restrict__ BB,
            uchar* __restrict__ qnb, uchar* __restrict__ kvb, int N) {
    __shared__ short As[128 * 128];
    int tid = threadIdx.x;
    int rowBlk = blockIdx.x;

    short8 av[8];
    int chunk = tid & 15;
    #pragma unroll
    for (int i = 0; i < 8; ++i) {
        int row = i * 16 + (tid >> 4);
        int gRow = rowBlk * 128 + row;
        if (gRow < N) av[i] = *(const short8*)(xnb + (size_t)gRow * 128 + chunk * 8);
        else          av[i] = short8{0, 0, 0, 0, 0, 0, 0, 0};
    }
    #pragma unroll
    for (int i = 0; i < 8; ++i) {
        int row = i * 16 + (tid >> 4);
        int widx = row * 128 + ((chunk * 8) ^ ((row & 7) * 8));
        *(short8*)&As[widx] = av[i];
    }
    __syncthreads();

    int wv = tid >> 6, lane = tid & 63;
    int wr = wv >> 1, wc = wv & 1;
    int l15 = lane & 15, g = lane >> 4;

    short8 af[4][4];
    #pragma unroll
    for (int kt = 0; kt < 4; ++kt) {
        int kshort = kt * 32 + g * 8;
        #pragma unroll
        for (int m = 0; m < 4; ++m) {
            int r = wr * 64 + m * 16 + l15;
            af[kt][m] = *(const short8*)&As[r * 128 + (kshort ^ ((r & 7) * 8))];
        }
    }

    for (int cb = 0; cb < 3; ++cb) {
        f32x4 acc[4][4];
        #pragma unroll
        for (int m = 0; m < 4; ++m)
            #pragma unroll
            for (int n = 0; n < 4; ++n) acc[m][n] = f32x4{0.f, 0.f, 0.f, 0.f};

        #pragma unroll
        for (int kt = 0; kt < 4; ++kt) {
            int kshort = kt * 32 + g * 8;
            short8 bf[4];
            #pragma unroll
            for (int n = 0; n < 4; ++n) {
                int col = cb * 128 + wc * 64 + n * 16 + l15;
                bf[n] = *(const short8*)(WTb + (size_t)col * 128 + kshort);
            }
            #pragma unroll
            for (int m = 0; m < 4; ++m)
                #pragma unroll
                for (int n = 0; n < 4; ++n)
                    acc[m][n] = __builtin_amdgcn_mfma_f32_16x16x32_bf16(af[kt][m], bf[n], acc[m][n], 0, 0, 0);
        }

        float bb[4];
        #pragma unroll
        for (int n = 0; n < 4; ++n) bb[n] = BB[cb * 128 + wc * 64 + n * 16 + l15];

        #pragma unroll
        for (int m = 0; m < 4; ++m) {
            int R0 = rowBlk * 128 + wr * 64 + m * 16 + g * 4;
            #pragma unroll
            for (int n = 0; n < 4; ++n) {
                int cl = wc * 64 + n * 16 + l15;
                #pragma unroll
                for (int r = 0; r < 4; ++r) {
                    int row = R0 + r;
                    if (row >= N) continue;
                    float val = acc[m][n][r] + bb[n];
                    if (cb == 0) {
                        qnb[(size_t)row * 128 + cl] = q8(val);
                    } else {
                        int off = ((cl >> 2) << 3) + (cl & 3) + ((cb == 2) ? 4 : 0);
                        kvb[(size_t)row * 256 + off] = q8(val);
                    }
                }
            }
        }
    }
}

// ================= single-kernel scan: block b sums chunks 0..b-1 itself (cnt L2-hot) ======
__global__ __launch_bounds__(256)
void k_scan(const int* __restrict__ cnt, int* __restrict__ rowptr) {
    __shared__ int sh[256];
    int b = blockIdx.x, t = threadIdx.x;
    // exclusive base: sum of all chunks before b
    int part = 0;
    for (int ch = 0; ch < b; ++ch) {
        int i = ch * 1024 + t * 4;
        part += cnt[i] + cnt[i + 1] + cnt[i + 2] + cnt[i + 3];
    }
    sh[t] = part;
    __syncthreads();
    for (int off = 128; off > 0; off >>= 1) {
        if (t < off) sh[t] += sh[t + off];
        __syncthreads();
    }
    int baseSum = sh[0];
    __syncthreads();
    // scan own chunk
    int base = b * 1024 + t * 4;
    int v0 = cnt[base], v1 = cnt[base + 1], v2 = cnt[base + 2], v3 = cnt[base + 3];
    int tot = v0 + v1 + v2 + v3;
    sh[t] = tot;
    __syncthreads();
    for (int off = 1; off < 256; off <<= 1) {
        int add = (t >= off) ? sh[t - off] : 0;
        __syncthreads();
        sh[t] += add;
        __syncthreads();
    }
    int excl = sh[t] - tot + baseSum;
    rowptr[base]     = excl;
    rowptr[base + 1] = excl + v0;
    rowptr[base + 2] = excl + v0 + v1;
    rowptr[base + 3] = excl + v0 + v1 + v2;
}

// ================= D4: atomic-free scatter (pos = rowptr[dst] + rank) =========
__global__ __launch_bounds__(256)
void k_scatter(const uint2* __restrict__ pp2, const float* __restrict__ ewt,
               const float* __restrict__ deg, const int* __restrict__ rowptr,
               uint2* __restrict__ erec, int E) {
    const float C = 0.25f * 1.4426950408889634f / 1008.0625f;  // /= 31.75^2
    int e = blockIdx.x * 256 + threadIdx.x;
    if (e >= E) return;
    uint2 P = pp2[e];
    int s = (int)(P.x & 0xffffu), dd = (int)(P.x >> 16);
    int rank = (int)(P.y & 0xffffu);
    uint ti = P.y >> 16;
    float dg = deg[s];
    float ewc = dg > 0.f ? ewt[e] * C / dg : 0.f;
    int pos = rowptr[dd] + rank;
    uint2 r;
    r.x = (uint)s | (ti << 16);
    r.y = __float_as_uint(ewc);
    erec[pos] = r;
}

// ================= D5: fused attention+aggr, half-wave pairing, int8 operands =================
#define AGGR_BODY(JJ, MASKED)                                                               \
    {                                                                                       \
        uint2 r = erec[(JJ) + ((MASKED) ? 0 : half)];                                       \
        int s = (int)(r.x & 0xffffu), ti = (int)(r.x >> 16);                                 \
        uint2 kv = *(const uint2*)(kvb + (size_t)s * 256 + 8 * c);                          \
        uint2 gg = *(const uint2*)(gkv + (size_t)ti * 256 + 8 * c);                         \
        float p = -Q256;                                                                    \
        p = fmaf((float)(kv.x & 0xffu)         + (float)(gg.x & 0xffu),         qf0, p);    \
        p = fmaf((float)((kv.x >> 8) & 0xffu)  + (float)((gg.x >> 8) & 0xffu),  qf1, p);    \
        p = fmaf((float)((kv.x >> 16) & 0xffu) + (float)((gg.x >> 16) & 0xffu), qf2, p);    \
        p = fmaf((float)(kv.x >> 24)           + (float)(gg.x >> 24),           qf3, p);    \
        p += __shfl_xor(p, 1);                                                              \
        p += __shfl_xor(p, 2);                                                              \
        float ex = fexp2(p * __uint_as_float(r.y));                                         \
        if (MASKED && half) ex = 0.f;                                                       \
        den += ex;                                                                          \
        n0 = fmaf(ex, (float)(kv.y & 0xffu)         + (float)(gg.y & 0xffu),         n0);   \
        n1 = fmaf(ex, (float)((kv.y >> 8) & 0xffu)  + (float)((gg.y >> 8) & 0xffu),  n1);   \
        n2 = fmaf(ex, (float)((kv.y >> 16) & 0xffu) + (float)((gg.y >> 16) & 0xffu), n2);   \
        n3 = fmaf(ex, (float)(kv.y >> 24)           + (float)(gg.y >> 24),           n3);   \
    }

__global__ __launch_bounds__(256)
void k_aggr(const int* __restrict__ rowptr, const uint2* __restrict__ erec,
            const uchar* __restrict__ qnb, const uchar* __restrict__ kvb,
            const uchar* __restrict__ gkv,
            const float4* __restrict__ x4, float4* __restrict__ out4, int N) {
    int w = (int)((blockIdx.x * (size_t)blockDim.x + threadIdx.x) >> 6);
    if (w >= N) return;
    int lane = threadIdx.x & 63;
    int c = lane & 31;
    int half = lane >> 5;

    uint qv = *(const uint*)(qnb + (size_t)w * 128 + 4 * c);
    float qf0 = (float)(qv & 0xffu) - 128.0f;
    float qf1 = (float)((qv >> 8) & 0xffu) - 128.0f;
    float qf2 = (float)((qv >> 16) & 0xffu) - 128.0f;
    float qf3 = (float)(qv >> 24) - 128.0f;
    float Q256 = 256.0f * (qf0 + qf1 + qf2 + qf3);

    float n0 = 0.f, n1 = 0.f, n2 = 0.f, n3 = 0.f, den = 0.f;
    int beg = rowptr[w], end = rowptr[w + 1];

    int j = beg;
    for (; j + 8 <= end; j += 8) {
        AGGR_BODY(j, 0)
        AGGR_BODY(j + 2, 0)
        AGGR_BODY(j + 4, 0)
        AGGR_BODY(j + 6, 0)
    }
    for (; j + 2 <= end; j += 2) AGGR_BODY(j, 0)
    if (j < end) AGGR_BODY(j, 1)

    den += __shfl_xor(den, 32);
    n0 += __shfl_xor(n0, 32);
    n1 += __shfl_xor(n1, 32);
    n2 += __shfl_xor(n2, 32);
    n3 += __shfl_xor(n3, 32);

    if (half == 0) {
        const float S = 1.0f / 31.75f;
        float inv  = den > 0.f ? frcp(den) : 0.f;
        float c256 = den > 0.f ? 256.f : 0.f;
        float a0 = S * (n0 * inv - c256);
        float a1 = S * (n1 * inv - c256);
        float a2 = S * (n2 * inv - c256);
        float a3 = S * (n3 * inv - c256);
        float4 xx = x4[(size_t)w * 32 + c];
        float4 o;
        o.x = xx.x + 0.5f * a0 * (1.0f + erff(a0 * 0.70710678118f));
        o.y = xx.y + 0.5f * a1 * (1.0f + erff(a1 * 0.70710678118f));
        o.z = xx.z + 0.5f * a2 * (1.0f + erff(a2 * 0.70710678118f));
        o.w = xx.w + 0.5f * a3 * (1.0f + erff(a3 * 0.70710678118f));
        out4[(size_t)w * 32 + c] = o;
    }
}

extern "C" void kernel_launch(void* const* d_in, const int* in_sizes, int n_in,
                              void* d_out, int out_size, void* d_ws, size_t ws_size,
                              hipStream_t stream) {
    const float* x    = (const float*)d_in[0];
    const int*   ei   = (const int*)d_in[1];
    const float* ewt  = (const float*)d_in[2];
    const float* etim = (const float*)d_in[4];
    const float* Wk   = (const float*)d_in[5];
    const float* bk   = (const float*)d_in[6];
    const float* Wq   = (const float*)d_in[7];
    const float* bq   = (const float*)d_in[8];
    const float* Wv   = (const float*)d_in[9];
    const float* bv   = (const float*)d_in[10];
    int N = in_sizes[3];
    int E = in_sizes[2];
    float* out = (float*)d_out;

    int NCH = (N + 1 + 1023) / 1024;          // 50
    int NP = NCH * 1024;

    char* base = (char*)d_ws;
    size_t off = 0;
    auto alloc = [&](size_t bytes) {
        char* r = base + off;
        off += (bytes + 255) & ~size_t(255);
        return r;
    };
    ushort* xnb = (ushort*)alloc((size_t)N * 128 * 2);   // bf16; dead after gemm; reused as erec
    uchar*  qnb = (uchar*)alloc((size_t)N * 128);
    uchar*  kvb = (uchar*)alloc((size_t)N * 256);
    uchar*  gkv = (uchar*)alloc((size_t)TBL * 256);
    ushort* WTb = (ushort*)alloc(384 * 128 * 2);
    float*  BB  = (float*)alloc(384 * 4);
    float*  deg = (float*)alloc((size_t)N * 4);          // deg+cnt adjacent: one memset
    int*    cnt = (int*)alloc((size_t)NP * 4);
    uint2*  pp2 = (uint2*)alloc((size_t)E * 8);
    int*    rowptr = (int*)alloc((size_t)NP * 4);
    uint2*  erec   = (uint2*)xnb;   // E*8 = 5.1MB <= N*256B = 12.8MB

    size_t zbytes = (size_t)((char*)(cnt + NP) - (char*)deg);
    hipMemsetAsync(deg, 0, zbytes, stream);

    // D1: homogeneous fused front, 1 edge/thread (best measured config).
    int EB = (E + 255) / 256;                 // 2500 edge blocks
    int FIX = TBL / 16 + 192;                 // 448 table+wp blocks
    int blocks = EB > FIX + 1 ? EB : FIX + 1;
    int lnBlocks = blocks - FIX;              // 2052
    int RPB = (N + lnBlocks - 1) / lnBlocks;  // 25 LN rows per block
    k_front<<<blocks, 256, 0, stream>>>((const float2*)x, (uint*)xnb,
                                        Wk, Wv, gkv, Wq, bq, bk, bv, WTb, BB,
                                        ei, ewt, etim, cnt, deg, pp2,
                                        N, E, RPB);

    // D2: gemm (A staged once, 3 output slices looped, B direct from L2)
    k_gemm<<<(N + 127) / 128, 256, 0, stream>>>(xnb, WTb, BB, qnb, kvb, N);

    // single-kernel scan
    k_scan<<<NCH, 256, 0, stream>>>(cnt, rowptr);

    // D4: atomic-free scatter
    k_scatter<<<(E + 255) / 256, 256, 0, stream>>>(pp2, ewt, deg, rowptr, erec, E);

    // D5: aggregate
    int agrid = (int)(((size_t)N * 64 + 255) / 256);
    k_aggr<<<agrid, 256, 0, stream>>>(rowptr, erec, qnb, kvb, gkv,
                                      (const float4*)x, (float4*)out, N);
}

// Round 20
// 169.952 us; speedup vs baseline: 1.0390x; 1.0390x over previous
//
#include <hip/hip_runtime.h>
#include <hip/hip_bf16.h>

constexpr int D_ = 128;
constexpr int DK_ = 16;
constexpr int TBL = 4096;

typedef __attribute__((ext_vector_type(8))) short short8;
typedef __attribute__((ext_vector_type(4))) float f32x4;
typedef unsigned char uchar;

__device__ __forceinline__ ushort f2b(float f) {
    uint b = __float_as_uint(f);
    uint r = (b + 0x7fffu + ((b >> 16) & 1u)) >> 16;
    return (ushort)r;
}
// fixed-scale biased int8: byte = clamp(round(v*31.75)+128, 0, 255)
__device__ __forceinline__ uchar q8(float v) {
    float t = fmaf(v, 31.75f, 128.5f);
    t = fminf(fmaxf(t, 0.0f), 255.0f);
    return (uchar)(uint)t;
}
__device__ __forceinline__ float fexp2(float x) {
#if __has_builtin(__builtin_amdgcn_exp2f)
    return __builtin_amdgcn_exp2f(x);
#else
    return exp2f(x);
#endif
}
__device__ __forceinline__ float frcp(float x) {
#if __has_builtin(__builtin_amdgcn_rcpf)
    return __builtin_amdgcn_rcpf(x);
#else
    return 1.0f / x;
#endif
}

// ================= D1: homogeneous fused front (1 edge/thread — best measured) =================
// EVERY block: (a) issue its 256-edge atomics (deg fire-and-forget, cnt rank-return),
// (b) VALU work (b<256: temporal table; 256<=b<448: W-prep; else: RPB LN rows),
// (c) write packed edge record using rank — atomic latency hidden under (b).
__global__ __launch_bounds__(256)
void k_front(const float2* __restrict__ x2, uint* __restrict__ xnb,
             const float* __restrict__ Wk, const float* __restrict__ Wv,
             uchar* __restrict__ gkv,
             const float* __restrict__ Wq, const float* __restrict__ bq,
             const float* __restrict__ bk, const float* __restrict__ bv,
             ushort* __restrict__ WTb, float* __restrict__ BB,
             const int* __restrict__ ei, const float* __restrict__ ewt,
             const float* __restrict__ etime,
             int* __restrict__ cnt, float* __restrict__ deg, uint2* __restrict__ pp2,
             int N, int E, int RPB) {
    __shared__ float te[16][128];
    __shared__ int sor;
    int b = blockIdx.x;
    int tid = threadIdx.x;
    int wv = tid >> 6, lane = tid & 63;

    // ---- phase A: edge atomics ----
    int2 det = ((const int2*)ei)[tid];   // fixed window, words < 512 <= 2E: safe both layouts
    if (tid == 0) sor = 0;
    __syncthreads();
    atomicOr(&sor, det.y);               // all odd words zero => int64 layout
    __syncthreads();
    int e = b * 256 + tid;
    bool act = (e < E);
    int s = 0, dd = 0, rank = 0;
    float t = 0.f;
    if (act) {
        if (sor == 0) { s = ((const int2*)ei)[e].x; dd = ((const int2*)ei)[E + e].x; }
        else          { s = ei[e];                  dd = ei[E + e]; }
        t = etime[e];
        atomicAdd(&deg[s], ewt[e]);          // fire-and-forget
        rank = atomicAdd(&cnt[dd], 1);       // return hidden under phase B
    }

    // ---- phase B: VALU work ----
    if (b < TBL / 16) {
        // temporal table -> gkv[TBL][256] int8 interleaved [k4|v4], 16 rows/block
        int t0 = b * 16;
        int j = tid & 127, half = tid >> 7;
        float freq = 200.0f * exp2f(-(float)(j >> 1) * (13.287712379549449f / 64.0f));
        bool isCos = (j & 1);
        #pragma unroll
        for (int bb = 0; bb < 8; ++bb) {
            float tt = (float)(t0 + half * 8 + bb) * (1.0f / (float)(TBL - 1));
            float arg = tt * freq;
            te[half * 8 + bb][j] = isCos ? cosf(arg) : sinf(arg);
        }
        __syncthreads();
        int h = j >> 4, kk = j & 15;
        float ak[8] = {}, av[8] = {};
        for (int d = 0; d < 128; ++d) {
            float wk = Wk[(h * 128 + d) * 16 + kk];
            float wvv = Wv[(h * 128 + d) * 16 + kk];
            float tvs[8];
            #pragma unroll
            for (int bb = 0; bb < 8; ++bb) tvs[bb] = te[half * 8 + bb][d];
            #pragma unroll
            for (int bb = 0; bb < 8; ++bb) { ak[bb] += tvs[bb] * wk; av[bb] += tvs[bb] * wvv; }
        }
        int off = ((j >> 2) << 3) + (j & 3);
        #pragma unroll
        for (int bb = 0; bb < 8; ++bb) {
            size_t row = (size_t)(t0 + half * 8 + bb);
            gkv[row * 256 + off]     = q8(ak[bb]);
            gkv[row * 256 + off + 4] = q8(av[bb]);
        }
    } else if (b < TBL / 16 + 192) {
        // WTb[384][128] bf16 (B^T), BB[384]; 192 blocks x 256 = 384*128
        int i = (b - TBL / 16) * 256 + tid;
        int c = i >> 7, d = i & 127;
        int m = c >> 7, cl = c & 127;
        int h = cl >> 4, kk = cl & 15;
        const float* W = (m == 0) ? Wq : ((m == 1) ? Wk : Wv);
        WTb[i] = f2b(W[(h * D_ + d) * DK_ + kk]);
        if (i < 384) {
            int m2 = i >> 7, cl2 = i & 127;
            const float* bb = (m2 == 0) ? bq : ((m2 == 1) ? bk : bv);
            BB[i] = bb[cl2];
        }
    } else {
        // LayerNorm: RPB rows per block, one row per wave per iteration
        int lnb = b - (TBL / 16 + 192);
        for (int i = 0;; ++i) {
            int rl = i * 4 + wv;
            if (rl >= RPB) break;
            int row = lnb * RPB + rl;
            if (row >= N) break;
            float2 v = x2[(size_t)row * 64 + lane];
            float sm = v.x + v.y;
            #pragma unroll
            for (int o = 1; o < 64; o <<= 1) sm += __shfl_xor(sm, o);
            float mu = sm * (1.0f / 128.0f);
            float dx = v.x - mu, dy = v.y - mu;
            float s2 = dx * dx + dy * dy;
            #pragma unroll
            for (int o = 1; o < 64; o <<= 1) s2 += __shfl_xor(s2, o);
            float rs = rsqrtf(s2 * (1.0f / 128.0f) + 1e-5f);
            uint lo = f2b(dx * rs), hi = f2b(dy * rs);
            xnb[(size_t)row * 64 + lane] = (hi << 16) | lo;
        }
    }

    // ---- phase C: packed edge record (rank's wait lands here, already drained) ----
    if (act) {
        int ti = (int)(t * (float)(TBL - 1) + 0.5f);
        ti = ti < 0 ? 0 : (ti > TBL - 1 ? TBL - 1 : ti);
        uint2 r;
        r.x = (uint)s | ((uint)dd << 16);    // N <= 65536
        r.y = (uint)rank | ((uint)ti << 16); // rank < 65536, ti < 4096
        pp2[e] = r;
    }
}

// ================= D2: MFMA GEMM (outputs int8 q / interleaved int8 kv) =================
__global__ __launch_bounds__(256)
void k_gemm(const ushort* __restrict__ xnb, const ushort* __restrict__ WTb,
            const float* __restrict__ BB,
            uchar* __restrict__ qnb, uchar* __restrict__ kvb, int N) {
    __shared__ short As[128 * 128];
    __shared__ short Bs[128 * 128];
    int tid = threadIdx.x;
    int rowBlk = blockIdx.x, cb = blockIdx.y;

    short8 av[8], bv[8];
    int chunk = tid & 15;
    #pragma unroll
    for (int i = 0; i < 8; ++i) {
        int row = i * 16 + (tid >> 4);
        int gRow = rowBlk * 128 + row;
        if (gRow < N) av[i] = *(const short8*)(xnb + (size_t)gRow * 128 + chunk * 8);
        else          av[i] = short8{0, 0, 0, 0, 0, 0, 0, 0};
        int gCol = cb * 128 + row;
        bv[i] = *(const short8*)(WTb + (size_t)gCol * 128 + chunk * 8);
    }
    #pragma unroll
    for (int i = 0; i < 8; ++i) {
        int row = i * 16 + (tid >> 4);
        int widx = row * 128 + ((chunk * 8) ^ ((row & 7) * 8));
        *(short8*)&As[widx] = av[i];
        *(short8*)&Bs[widx] = bv[i];
    }
    __syncthreads();

    int wv = tid >> 6, lane = tid & 63;
    int wr = wv >> 1, wc = wv & 1;
    int l15 = lane & 15, g = lane >> 4;

    f32x4 acc[4][4];
    #pragma unroll
    for (int m = 0; m < 4; ++m)
        #pragma unroll
        for (int n = 0; n < 4; ++n) acc[m][n] = f32x4{0.f, 0.f, 0.f, 0.f};

    #pragma unroll
    for (int kt = 0; kt < 4; ++kt) {
        int kshort = kt * 32 + g * 8;
        short8 af[4], bf[4];
        #pragma unroll
        for (int m = 0; m < 4; ++m) {
            int r = wr * 64 + m * 16 + l15;
            af[m] = *(const short8*)&As[r * 128 + (kshort ^ ((r & 7) * 8))];
        }
        #pragma unroll
        for (int n = 0; n < 4; ++n) {
            int c = wc * 64 + n * 16 + l15;
            bf[n] = *(const short8*)&Bs[c * 128 + (kshort ^ ((c & 7) * 8))];
        }
        #pragma unroll
        for (int m = 0; m < 4; ++m)
            #pragma unroll
            for (int n = 0; n < 4; ++n)
                acc[m][n] = __builtin_amdgcn_mfma_f32_16x16x32_bf16(af[m], bf[n], acc[m][n], 0, 0, 0);
    }

    float bb[4];
    #pragma unroll
    for (int n = 0; n < 4; ++n) bb[n] = BB[cb * 128 + wc * 64 + n * 16 + l15];

    #pragma unroll
    for (int m = 0; m < 4; ++m) {
        int R0 = rowBlk * 128 + wr * 64 + m * 16 + g * 4;
        #pragma unroll
        for (int n = 0; n < 4; ++n) {
            int cl = wc * 64 + n * 16 + l15;
            #pragma unroll
            for (int r = 0; r < 4; ++r) {
                int row = R0 + r;
                if (row >= N) continue;
                float val = acc[m][n][r] + bb[n];
                if (cb == 0) {
                    qnb[(size_t)row * 128 + cl] = q8(val);
                } else {
                    int off = ((cl >> 2) << 3) + (cl & 3) + ((cb == 2) ? 4 : 0);
                    kvb[(size_t)row * 256 + off] = q8(val);
                }
            }
        }
    }
}

// ================= scan: 2 kernels (scanB folded into scanC via wave reduce) ===========
__global__ __launch_bounds__(256)
void k_scanA(const int* __restrict__ cnt, int* __restrict__ csum) {
    __shared__ int sh[256];
    int b = blockIdx.x, t = threadIdx.x;
    int base = b * 1024 + t * 4;
    int s = cnt[base] + cnt[base + 1] + cnt[base + 2] + cnt[base + 3];
    sh[t] = s;
    __syncthreads();
    for (int off = 128; off > 0; off >>= 1) {
        if (t < off) sh[t] += sh[t + off];
        __syncthreads();
    }
    if (t == 0) csum[b] = sh[0];
}

// requires nch <= 64
__global__ __launch_bounds__(256)
void k_scanC(const int* __restrict__ cnt, const int* __restrict__ csum,
             int* __restrict__ rowptr, int nch) {
    __shared__ int sh[256];
    __shared__ int sExcl;
    int b = blockIdx.x, t = threadIdx.x;
    if (t < 64) {
        int v = (t < b && t < nch) ? csum[t] : 0;
        #pragma unroll
        for (int o = 1; o < 64; o <<= 1) v += __shfl_xor(v, o);
        if (t == 0) sExcl = v;
    }
    int base = b * 1024 + t * 4;
    int v0 = cnt[base], v1 = cnt[base + 1], v2 = cnt[base + 2], v3 = cnt[base + 3];
    int tot = v0 + v1 + v2 + v3;
    sh[t] = tot;
    __syncthreads();
    for (int off = 1; off < 256; off <<= 1) {
        int add = (t >= off) ? sh[t - off] : 0;
        __syncthreads();
        sh[t] += add;
        __syncthreads();
    }
    int excl = sh[t] - tot + sExcl;
    rowptr[base]     = excl;
    rowptr[base + 1] = excl + v0;
    rowptr[base + 2] = excl + v0 + v1;
    rowptr[base + 3] = excl + v0 + v1 + v2;
}

// ================= D4: atomic-free scatter (pos = rowptr[dst] + rank) =========
__global__ __launch_bounds__(256)
void k_scatter(const uint2* __restrict__ pp2, const float* __restrict__ ewt,
               const float* __restrict__ deg, const int* __restrict__ rowptr,
               uint2* __restrict__ erec, int E) {
    const float C = 0.25f * 1.4426950408889634f / 1008.0625f;  // /= 31.75^2
    int e = blockIdx.x * 256 + threadIdx.x;
    if (e >= E) return;
    uint2 P = pp2[e];
    int s = (int)(P.x & 0xffffu), dd = (int)(P.x >> 16);
    int rank = (int)(P.y & 0xffffu);
    uint ti = P.y >> 16;
    float dg = deg[s];
    float ewc = dg > 0.f ? ewt[e] * C / dg : 0.f;
    int pos = rowptr[dd] + rank;
    uint2 r;
    r.x = (uint)s | (ti << 16);
    r.y = __float_as_uint(ewc);
    erec[pos] = r;
}

// ================= D5: fused attention+aggr, half-wave pairing, int8 operands =================
#define AGGR_BODY(JJ, MASKED)                                                               \
    {                                                                                       \
        uint2 r = erec[(JJ) + ((MASKED) ? 0 : half)];                                       \
        int s = (int)(r.x & 0xffffu), ti = (int)(r.x >> 16);                                 \
        uint2 kv = *(const uint2*)(kvb + (size_t)s * 256 + 8 * c);                          \
        uint2 gg = *(const uint2*)(gkv + (size_t)ti * 256 + 8 * c);                         \
        float p = -Q256;                                                                    \
        p = fmaf((float)(kv.x & 0xffu)         + (float)(gg.x & 0xffu),         qf0, p);    \
        p = fmaf((float)((kv.x >> 8) & 0xffu)  + (float)((gg.x >> 8) & 0xffu),  qf1, p);    \
        p = fmaf((float)((kv.x >> 16) & 0xffu) + (float)((gg.x >> 16) & 0xffu), qf2, p);    \
        p = fmaf((float)(kv.x >> 24)           + (float)(gg.x >> 24),           qf3, p);    \
        p += __shfl_xor(p, 1);                                                              \
        p += __shfl_xor(p, 2);                                                              \
        float ex = fexp2(p * __uint_as_float(r.y));                                         \
        if (MASKED && half) ex = 0.f;                                                       \
        den += ex;                                                                          \
        n0 = fmaf(ex, (float)(kv.y & 0xffu)         + (float)(gg.y & 0xffu),         n0);   \
        n1 = fmaf(ex, (float)((kv.y >> 8) & 0xffu)  + (float)((gg.y >> 8) & 0xffu),  n1);   \
        n2 = fmaf(ex, (float)((kv.y >> 16) & 0xffu) + (float)((gg.y >> 16) & 0xffu), n2);   \
        n3 = fmaf(ex, (float)(kv.y >> 24)           + (float)(gg.y >> 24),           n3);   \
    }

__global__ __launch_bounds__(256)
void k_aggr(const int* __restrict__ rowptr, const uint2* __restrict__ erec,
            const uchar* __restrict__ qnb, const uchar* __restrict__ kvb,
            const uchar* __restrict__ gkv,
            const float4* __restrict__ x4, float4* __restrict__ out4, int N) {
    int w = (int)((blockIdx.x * (size_t)blockDim.x + threadIdx.x) >> 6);
    if (w >= N) return;
    int lane = threadIdx.x & 63;
    int c = lane & 31;
    int half = lane >> 5;

    uint qv = *(const uint*)(qnb + (size_t)w * 128 + 4 * c);
    float qf0 = (float)(qv & 0xffu) - 128.0f;
    float qf1 = (float)((qv >> 8) & 0xffu) - 128.0f;
    float qf2 = (float)((qv >> 16) & 0xffu) - 128.0f;
    float qf3 = (float)(qv >> 24) - 128.0f;
    float Q256 = 256.0f * (qf0 + qf1 + qf2 + qf3);

    float n0 = 0.f, n1 = 0.f, n2 = 0.f, n3 = 0.f, den = 0.f;
    int beg = rowptr[w], end = rowptr[w + 1];

    int j = beg;
    for (; j + 8 <= end; j += 8) {
        AGGR_BODY(j, 0)
        AGGR_BODY(j + 2, 0)
        AGGR_BODY(j + 4, 0)
        AGGR_BODY(j + 6, 0)
    }
    for (; j + 2 <= end; j += 2) AGGR_BODY(j, 0)
    if (j < end) AGGR_BODY(j, 1)

    den += __shfl_xor(den, 32);
    n0 += __shfl_xor(n0, 32);
    n1 += __shfl_xor(n1, 32);
    n2 += __shfl_xor(n2, 32);
    n3 += __shfl_xor(n3, 32);

    if (half == 0) {
        const float S = 1.0f / 31.75f;
        float inv  = den > 0.f ? frcp(den) : 0.f;
        float c256 = den > 0.f ? 256.f : 0.f;
        float a0 = S * (n0 * inv - c256);
        float a1 = S * (n1 * inv - c256);
        float a2 = S * (n2 * inv - c256);
        float a3 = S * (n3 * inv - c256);
        float4 xx = x4[(size_t)w * 32 + c];
        float4 o;
        o.x = xx.x + 0.5f * a0 * (1.0f + erff(a0 * 0.70710678118f));
        o.y = xx.y + 0.5f * a1 * (1.0f + erff(a1 * 0.70710678118f));
        o.z = xx.z + 0.5f * a2 * (1.0f + erff(a2 * 0.70710678118f));
        o.w = xx.w + 0.5f * a3 * (1.0f + erff(a3 * 0.70710678118f));
        out4[(size_t)w * 32 + c] = o;
    }
}

extern "C" void kernel_launch(void* const* d_in, const int* in_sizes, int n_in,
                              void* d_out, int out_size, void* d_ws, size_t ws_size,
                              hipStream_t stream) {
    const float* x    = (const float*)d_in[0];
    const int*   ei   = (const int*)d_in[1];
    const float* ewt  = (const float*)d_in[2];
    const float* etim = (const float*)d_in[4];
    const float* Wk   = (const float*)d_in[5];
    const float* bk   = (const float*)d_in[6];
    const float* Wq   = (const float*)d_in[7];
    const float* bq   = (const float*)d_in[8];
    const float* Wv   = (const float*)d_in[9];
    const float* bv   = (const float*)d_in[10];
    int N = in_sizes[3];
    int E = in_sizes[2];
    float* out = (float*)d_out;

    int NCH = (N + 1 + 1023) / 1024;          // 50 (<= 64 required by k_scanC)
    int NP = NCH * 1024;

    char* base = (char*)d_ws;
    size_t off = 0;
    auto alloc = [&](size_t bytes) {
        char* r = base + off;
        off += (bytes + 255) & ~size_t(255);
        return r;
    };
    ushort* xnb = (ushort*)alloc((size_t)N * 128 * 2);   // bf16; dead after gemm; reused as erec
    uchar*  qnb = (uchar*)alloc((size_t)N * 128);
    uchar*  kvb = (uchar*)alloc((size_t)N * 256);
    uchar*  gkv = (uchar*)alloc((size_t)TBL * 256);
    ushort* WTb = (ushort*)alloc(384 * 128 * 2);
    float*  BB  = (float*)alloc(384 * 4);
    float*  deg = (float*)alloc((size_t)N * 4);
    uint2*  pp2 = (uint2*)alloc((size_t)E * 8);
    int*    cnt    = (int*)alloc((size_t)NP * 4);
    int*    rowptr = (int*)alloc((size_t)NP * 4);
    int*    csum   = (int*)alloc((size_t)NCH * 4);
    uint2*  erec   = (uint2*)xnb;   // E*8 = 5.1MB <= N*256B = 12.8MB

    hipMemsetAsync(cnt, 0, (size_t)NP * sizeof(int), stream);
    hipMemsetAsync(deg, 0, (size_t)N * sizeof(float), stream);

    // D1: homogeneous fused front, 1 edge/thread (best measured config).
    int EB = (E + 255) / 256;                 // 2500 edge blocks
    int FIX = TBL / 16 + 192;                 // 448 table+wp blocks
    int blocks = EB > FIX + 1 ? EB : FIX + 1;
    int lnBlocks = blocks - FIX;              // 2052
    int RPB = (N + lnBlocks - 1) / lnBlocks;  // 25 LN rows per block
    k_front<<<blocks, 256, 0, stream>>>((const float2*)x, (uint*)xnb,
                                        Wk, Wv, gkv, Wq, bq, bk, bv, WTb, BB,
                                        ei, ewt, etim, cnt, deg, pp2,
                                        N, E, RPB);

    // D2: gemm
    dim3 ggrid((N + 127) / 128, 3);
    k_gemm<<<ggrid, 256, 0, stream>>>(xnb, WTb, BB, qnb, kvb, N);

    // scan (2 kernels)
    k_scanA<<<NCH, 256, 0, stream>>>(cnt, csum);
    k_scanC<<<NCH, 256, 0, stream>>>(cnt, csum, rowptr, NCH);

    // D4: atomic-free scatter
    k_scatter<<<(E + 255) / 256, 256, 0, stream>>>(pp2, ewt, deg, rowptr, erec, E);

    // D5: aggregate
    int agrid = (int)(((size_t)N * 64 + 255) / 256);
    k_aggr<<<agrid, 256, 0, stream>>>(rowptr, erec, qnb, kvb, gkv,
                                      (const float4*)x, (float4*)out, N);
}